// Round 3
// baseline (1006.716 us; speedup 1.0000x reference)
//
#include <hip/hip_runtime.h>
#include <hip/hip_bf16.h>

#define N_NODES 50000
#define N_EDGES 800000
#define IN_DIM 256
#define HID 64
#define HEADS 4
#define OUT_DIM 16
#define GAT_IN 66   // HID + N_PROTO

typedef unsigned short u16;
typedef unsigned int u32;

__device__ __forceinline__ float bf2f(u16 u) {
  union { u32 i; float f; } v; v.i = ((u32)u) << 16; return v.f;
}
__device__ __forceinline__ u16 f2bf(float f) {
  union { float f; u32 i; } v; v.f = f;
  u32 r = v.i + 0x7FFFu + ((v.i >> 16) & 1u);
  return (u16)(r >> 16);
}
// dtype-agnostic float load: isbf!=0 -> buffer is bf16, else fp32
__device__ __forceinline__ float LD(const void* p, long i, int isbf) {
  return isbf ? bf2f(((const u16*)p)[i]) : ((const float*)p)[i];
}

// ---------------------------------------------------------------------------
// K0: zero deg[]; detect float dtype of x (bf16 vs fp32) and int dtype of
// edge_index (int64 vs int32).
// ---------------------------------------------------------------------------
__global__ void k_detect(const void* __restrict__ x, const void* __restrict__ ei,
                         int* __restrict__ flag_f, int* __restrict__ flag_i,
                         int* __restrict__ deg) {
  int i = blockIdx.x * 256 + threadIdx.x;
  if (i < N_NODES) deg[i] = 0;
  if (blockIdx.x == 0 && threadIdx.x == 0) {
    // float dtype: bf16 N(0,1) values have exponent field ~[100,135] nearly
    // always; fp32 read as u16 pairs has uniform low-halves (~57% overall).
    const u16* w = (const u16*)x;
    int cnt = 0;
    for (int k = 0; k < 256; k++) {
      int e = (w[k] >> 7) & 0xFF;
      if (e >= 100 && e <= 135) cnt++;
    }
    *flag_f = (cnt >= 200) ? 1 : 0;
    // int dtype: genuine int64 node ids are all in [0, N_NODES)
    const long long* e64 = (const long long*)ei;
    int ok = 1;
    for (int k = 0; k < 64; k++) {
      long long v = e64[k];
      if (v < 0 || v >= N_NODES) { ok = 0; break; }
    }
    *flag_i = ok;
  }
}

// ---------------------------------------------------------------------------
// K1: h = relu(x @ W_in + b_in); sem = cosine sim vs prototypes.
// One wave per node, lane c owns channel c. ha row (fp32): [h(64)|sem(2)].
// ---------------------------------------------------------------------------
__global__ __launch_bounds__(256) void k_haug(
    const void* __restrict__ x, const void* __restrict__ Win,
    const void* __restrict__ bin, const void* __restrict__ proto,
    const int* __restrict__ flag_f, float* __restrict__ ha)
{
  const int isbf = *flag_f;
  const int lane = threadIdx.x & 63;
  const int n = blockIdx.x * 4 + (threadIdx.x >> 6);
  if (n >= N_NODES) return;
  float acc = LD(bin, lane, isbf);
  for (int k = 0; k < IN_DIM; k++) {
    acc += LD(x, (long)n * IN_DIM + k, isbf) * LD(Win, (long)k * HID + lane, isbf);
  }
  float h = fmaxf(acc, 0.f);
  const float p0 = LD(proto, lane, isbf);
  const float p1 = LD(proto, HID + lane, isbf);
  float r0 = h * h, r1 = h * p0, r2 = h * p1, q0 = p0 * p0, q1 = p1 * p1;
  #pragma unroll
  for (int m = 1; m < 64; m <<= 1) {
    r0 += __shfl_xor(r0, m); r1 += __shfl_xor(r1, m); r2 += __shfl_xor(r2, m);
    q0 += __shfl_xor(q0, m); q1 += __shfl_xor(q1, m);
  }
  float* row = ha + (size_t)n * 68;
  row[lane] = h;
  if (lane == 0) {
    float hn = sqrtf(r0) + 1e-12f;
    row[64] = r1 / (hn * (sqrtf(q0) + 1e-12f));
    row[65] = r2 / (hn * (sqrtf(q1) + 1e-12f));
  }
}

// ---------------------------------------------------------------------------
// K2: xl = ha @ W_l + b_l, stored bf16 as xls[n*256 + c*4 + h] so the edge
// gather in k_agg is one ushort4 per lane.
// ---------------------------------------------------------------------------
__global__ __launch_bounds__(256) void k_xl(
    const float* __restrict__ ha, const void* __restrict__ Wl,
    const void* __restrict__ bl, const int* __restrict__ flag_f,
    u16* __restrict__ xls)
{
  const int isbf = *flag_f;
  const int lane = threadIdx.x & 63;
  const int n = blockIdx.x * 4 + (threadIdx.x >> 6);
  if (n >= N_NODES) return;
  const float* row = ha + (size_t)n * 68;
  float a0 = LD(bl, lane, isbf);
  float a1 = LD(bl, 64 + lane, isbf);
  float a2 = LD(bl, 128 + lane, isbf);
  float a3 = LD(bl, 192 + lane, isbf);
  for (int i = 0; i < GAT_IN; i++) {
    float hv = row[i];
    a0 += hv * LD(Wl, (long)i * 256 + lane, isbf);
    a1 += hv * LD(Wl, (long)i * 256 + 64 + lane, isbf);
    a2 += hv * LD(Wl, (long)i * 256 + 128 + lane, isbf);
    a3 += hv * LD(Wl, (long)i * 256 + 192 + lane, isbf);
  }
  ushort4 o;
  o.x = f2bf(a0); o.y = f2bf(a1); o.z = f2bf(a2); o.w = f2bf(a3);
  *(ushort4*)(xls + (size_t)n * 256 + lane * 4) = o;
}

// --------------------------- CSR construction ------------------------------
__global__ void k_hist(const void* __restrict__ ei, const int* __restrict__ flag_i,
                       int* __restrict__ deg) {
  int e = blockIdx.x * 256 + threadIdx.x;
  if (e >= N_EDGES) return;
  int d;
  if (*flag_i) d = (int)((const long long*)ei)[N_EDGES + e];
  else         d = ((const int*)ei)[N_EDGES + e];
  if ((unsigned)d < N_NODES) atomicAdd(&deg[d], 1);
}

__global__ __launch_bounds__(256) void k_scan(
    const int* __restrict__ deg, int* __restrict__ off, int* __restrict__ cur)
{
  __shared__ int part[256];
  const int t = threadIdx.x;
  const int CH = 196;  // 256*196 = 50176 >= 50000
  int base = t * CH;
  int s = 0;
  for (int i = 0; i < CH; i++) { int id = base + i; if (id < N_NODES) s += deg[id]; }
  part[t] = s;
  __syncthreads();
  for (int d = 1; d < 256; d <<= 1) {
    int v = part[t];
    int w = (t >= d) ? part[t - d] : 0;
    __syncthreads();
    part[t] = v + w;
    __syncthreads();
  }
  int pre = (t > 0) ? part[t - 1] : 0;
  for (int i = 0; i < CH; i++) {
    int id = base + i;
    if (id < N_NODES) { off[id] = pre; cur[id] = pre; pre += deg[id]; }
  }
  if (t == 255) off[N_NODES] = part[255];
}

__global__ void k_scatter(const void* __restrict__ ei, const int* __restrict__ flag_i,
                          int* __restrict__ cur, int* __restrict__ esrc) {
  int e = blockIdx.x * 256 + threadIdx.x;
  if (e >= N_EDGES) return;
  int s, d;
  if (*flag_i) {
    s = (int)((const long long*)ei)[e];
    d = (int)((const long long*)ei)[N_EDGES + e];
  } else {
    s = ((const int*)ei)[e];
    d = ((const int*)ei)[N_EDGES + e];
  }
  if ((unsigned)d >= N_NODES) return;
  if ((unsigned)s >= N_NODES) s = 0;
  int p = atomicAdd(&cur[d], 1);
  if ((unsigned)p < N_EDGES) esrc[p] = s;
}

// ---------------------------------------------------------------------------
// K5: per-dst-node: xr inline, online-softmax over CSR edges + self-loop,
// head-mean + relu + classifier. One wave per node, lane c owns channel c.
// ---------------------------------------------------------------------------
__global__ __launch_bounds__(256) void k_agg(
    const u16* __restrict__ xls, const float* __restrict__ ha,
    const void* __restrict__ Wr, const void* __restrict__ br,
    const int* __restrict__ esrc, const int* __restrict__ off,
    const void* __restrict__ att, const void* __restrict__ gbias,
    const void* __restrict__ wcls, const void* __restrict__ bcls,
    const int* __restrict__ flag_f, void* __restrict__ out)
{
  const int isbf = *flag_f;
  const int lane = threadIdx.x & 63;
  const int n = blockIdx.x * 4 + (threadIdx.x >> 6);
  if (n >= N_NODES) return;

  // xr[n][h][lane] computed inline from ha[n]
  const float* hrow = ha + (size_t)n * 68;
  float xr0 = LD(br, lane, isbf);
  float xr1 = LD(br, 64 + lane, isbf);
  float xr2 = LD(br, 128 + lane, isbf);
  float xr3 = LD(br, 192 + lane, isbf);
  for (int i = 0; i < GAT_IN; i++) {
    float hv = hrow[i];
    xr0 += hv * LD(Wr, (long)i * 256 + lane, isbf);
    xr1 += hv * LD(Wr, (long)i * 256 + 64 + lane, isbf);
    xr2 += hv * LD(Wr, (long)i * 256 + 128 + lane, isbf);
    xr3 += hv * LD(Wr, (long)i * 256 + 192 + lane, isbf);
  }

  const float at0 = LD(att, lane, isbf);
  const float at1 = LD(att, 64 + lane, isbf);
  const float at2 = LD(att, 128 + lane, isbf);
  const float at3 = LD(att, 192 + lane, isbf);

  float m0 = -1e30f, m1 = -1e30f, m2 = -1e30f, m3 = -1e30f;
  float l0 = 0.f, l1 = 0.f, l2 = 0.f, l3 = 0.f;
  float c0 = 0.f, c1 = 0.f, c2 = 0.f, c3 = 0.f;

  int kb = off[n], ke = off[n + 1];
  if (kb < 0) kb = 0;
  if (ke > N_EDGES) ke = N_EDGES;
  if (ke < kb) ke = kb;

  for (int k = kb - 1; k < ke; k++) {
    const int s = (k < kb) ? n : esrc[k];   // self-loop first, then CSR edges
    ushort4 xlv = *(const ushort4*)(xls + (size_t)s * 256 + lane * 4);
    const float x0 = bf2f(xlv.x), x1 = bf2f(xlv.y), x2 = bf2f(xlv.z), x3 = bf2f(xlv.w);
    float t0 = x0 + xr0, t1 = x1 + xr1, t2 = x2 + xr2, t3 = x3 + xr3;
    t0 = (t0 > 0.f) ? t0 : 0.2f * t0;
    t1 = (t1 > 0.f) ? t1 : 0.2f * t1;
    t2 = (t2 > 0.f) ? t2 : 0.2f * t2;
    t3 = (t3 > 0.f) ? t3 : 0.2f * t3;
    float g0 = at0 * t0, g1 = at1 * t1, g2 = at2 * t2, g3 = at3 * t3;
    #pragma unroll
    for (int mm = 1; mm < 64; mm <<= 1) {
      g0 += __shfl_xor(g0, mm);
      g1 += __shfl_xor(g1, mm);
      g2 += __shfl_xor(g2, mm);
      g3 += __shfl_xor(g3, mm);
    }
    float nm, sc, a;
    nm = fmaxf(m0, g0); sc = __expf(m0 - nm); a = __expf(g0 - nm);
    l0 = l0 * sc + a; c0 = c0 * sc + a * x0; m0 = nm;
    nm = fmaxf(m1, g1); sc = __expf(m1 - nm); a = __expf(g1 - nm);
    l1 = l1 * sc + a; c1 = c1 * sc + a * x1; m1 = nm;
    nm = fmaxf(m2, g2); sc = __expf(m2 - nm); a = __expf(g2 - nm);
    l2 = l2 * sc + a; c2 = c2 * sc + a * x2; m2 = nm;
    nm = fmaxf(m3, g3); sc = __expf(m3 - nm); a = __expf(g3 - nm);
    l3 = l3 * sc + a; c3 = c3 * sc + a * x3; m3 = nm;
  }

  float v = c0 / (l0 + 1e-16f) + c1 / (l1 + 1e-16f) +
            c2 / (l2 + 1e-16f) + c3 / (l3 + 1e-16f);
  v = fmaxf(0.25f * v + LD(gbias, lane, isbf), 0.f);

  float o16[16];
  #pragma unroll
  for (int o = 0; o < 16; o++) o16[o] = v * LD(wcls, lane * 16 + o, isbf);
  #pragma unroll
  for (int mm = 1; mm < 64; mm <<= 1) {
    #pragma unroll
    for (int o = 0; o < 16; o++) o16[o] += __shfl_xor(o16[o], mm);
  }
  if (lane < 16) {
    float r = o16[lane] + LD(bcls, lane, isbf);
    if (isbf) ((u16*)out)[(size_t)n * 16 + lane] = f2bf(r);
    else      ((float*)out)[(size_t)n * 16 + lane] = r;
  }
}

// ---------------------------------------------------------------------------
extern "C" void kernel_launch(void* const* d_in, const int* in_sizes, int n_in,
                              void* d_out, int out_size, void* d_ws, size_t ws_size,
                              hipStream_t stream)
{
  const void* x     = d_in[0];
  const void* ei    = d_in[1];
  const void* Win   = d_in[2];
  const void* bin   = d_in[3];
  const void* proto = d_in[4];
  const void* Wl    = d_in[5];
  const void* bl    = d_in[6];
  const void* Wr    = d_in[7];
  const void* br    = d_in[8];
  const void* att   = d_in[9];
  const void* gbias = d_in[10];
  const void* wcls  = d_in[11];
  const void* bcls  = d_in[12];

  // workspace carve-up, 256-B aligned regions, total ~43 MB
  char* p = (char*)d_ws;
  int* flag_f = (int*)p;               p += 256;
  int* flag_i = (int*)p;               p += 256;
  int* deg  = (int*)p;                 p += (N_NODES * 4 + 255) & ~255;
  int* off  = (int*)p;                 p += ((N_NODES + 1) * 4 + 255) & ~255;
  int* cur  = (int*)p;                 p += (N_NODES * 4 + 255) & ~255;
  int* esrc = (int*)p;                 p += (N_EDGES * 4 + 255) & ~255;
  float* ha = (float*)p;               p += ((size_t)N_NODES * 68 * 4 + 255) & ~255;
  u16* xls  = (u16*)p;                 p += (size_t)N_NODES * 256 * 2;

  k_detect<<<196, 256, 0, stream>>>(x, ei, flag_f, flag_i, deg);
  k_haug<<<12500, 256, 0, stream>>>(x, Win, bin, proto, flag_f, ha);
  k_hist<<<3125, 256, 0, stream>>>(ei, flag_i, deg);
  k_xl<<<12500, 256, 0, stream>>>(ha, Wl, bl, flag_f, xls);
  k_scan<<<1, 256, 0, stream>>>(deg, off, cur);
  k_scatter<<<3125, 256, 0, stream>>>(ei, flag_i, cur, esrc);
  k_agg<<<12500, 256, 0, stream>>>(xls, ha, Wr, br, esrc, off, att, gbias,
                                   wcls, bcls, flag_f, d_out);
}

// Round 4
// 653.743 us; speedup vs baseline: 1.5399x; 1.5399x over previous
//
#include <hip/hip_runtime.h>

#define N_NODES 50000
#define N_EDGES 800000
#define IN_DIM 256
#define HID 64
#define OUT_DIM 16
#define GAT_IN 66   // HID + N_PROTO

typedef unsigned short u16;
typedef unsigned int u32;

__device__ __forceinline__ float bf2f(u16 u) {
  union { u32 i; float f; } v; v.i = ((u32)u) << 16; return v.f;
}
__device__ __forceinline__ u16 f2bf(float f) {
  union { float f; u32 i; } v; v.f = f;
  u32 r = v.i + 0x7FFFu + ((v.i >> 16) & 1u);
  return (u16)(r >> 16);
}

// ---------------------------------------------------------------------------
// K0: zero deg[]; detect int dtype of edge_index (int64 vs int32).
// ---------------------------------------------------------------------------
__global__ void k_detect(const void* __restrict__ ei, int* __restrict__ flag_i,
                         int* __restrict__ deg) {
  int i = blockIdx.x * 256 + threadIdx.x;
  if (i < N_NODES) deg[i] = 0;
  if (blockIdx.x == 0 && threadIdx.x == 0) {
    const long long* e64 = (const long long*)ei;
    int ok = 1;
    for (int k = 0; k < 64; k++) {
      long long v = e64[k];
      if (v < 0 || v >= N_NODES) { ok = 0; break; }
    }
    *flag_i = ok;
  }
}

// ---------------------------------------------------------------------------
// K1: h = relu(x @ W_in + b_in); sem = cosine sim vs prototypes.
// W_in staged bf16 in LDS, transposed: wlds[(g*64+c)*4+j] = Win[(4g+j)*64+c].
// 4 waves/block, each wave processes 4 nodes at a time (amortizes ds_read).
// ha row (fp32): [h(64) | sem(2)], stride 68.
// ---------------------------------------------------------------------------
__global__ __launch_bounds__(256) void k_haug(
    const float* __restrict__ x, const float* __restrict__ Win,
    const float* __restrict__ bin, const float* __restrict__ proto,
    float* __restrict__ ha)
{
  __shared__ u16 wlds[IN_DIM * HID];  // 32 KB
  for (int m = threadIdx.x; m < IN_DIM * HID; m += 256) {
    int g = m >> 8, c = (m >> 2) & 63, j = m & 3;
    wlds[m] = f2bf(Win[(g * 4 + j) * 64 + c]);
  }
  __syncthreads();
  const int lane = threadIdx.x & 63;
  const int gid = blockIdx.x * 4 + (threadIdx.x >> 6);  // 5000 groups
  const float binc = bin[lane];
  const float p0 = proto[lane], p1 = proto[64 + lane];
  float q0 = p0 * p0, q1 = p1 * p1;
  #pragma unroll
  for (int mm = 1; mm < 64; mm <<= 1) { q0 += __shfl_xor(q0, mm); q1 += __shfl_xor(q1, mm); }
  const float ip0 = 1.f / (sqrtf(q0) + 1e-12f);
  const float ip1 = 1.f / (sqrtf(q1) + 1e-12f);

  for (int nb = gid * 4; nb < N_NODES; nb += 20000) {
    const float* x0 = x + (size_t)nb * IN_DIM;
    const float* x1 = x0 + IN_DIM;
    const float* x2 = x1 + IN_DIM;
    const float* x3 = x2 + IN_DIM;
    float a0 = 0.f, a1 = 0.f, a2 = 0.f, a3 = 0.f;
    #pragma unroll 4
    for (int g = 0; g < 64; ++g) {
      ushort4 wv = *(const ushort4*)&wlds[(g * 64 + lane) * 4];
      float w0 = bf2f(wv.x), w1 = bf2f(wv.y), w2 = bf2f(wv.z), w3 = bf2f(wv.w);
      float4 v0 = *(const float4*)(x0 + g * 4);
      float4 v1 = *(const float4*)(x1 + g * 4);
      float4 v2 = *(const float4*)(x2 + g * 4);
      float4 v3 = *(const float4*)(x3 + g * 4);
      a0 += v0.x * w0 + v0.y * w1 + v0.z * w2 + v0.w * w3;
      a1 += v1.x * w0 + v1.y * w1 + v1.z * w2 + v1.w * w3;
      a2 += v2.x * w0 + v2.y * w1 + v2.z * w2 + v2.w * w3;
      a3 += v3.x * w0 + v3.y * w1 + v3.z * w2 + v3.w * w3;
    }
    float accs[4] = {a0, a1, a2, a3};
    #pragma unroll
    for (int k = 0; k < 4; ++k) {
      float h = fmaxf(accs[k] + binc, 0.f);
      float r0 = h * h, r1 = h * p0, r2 = h * p1;
      #pragma unroll
      for (int mm = 1; mm < 64; mm <<= 1) {
        r0 += __shfl_xor(r0, mm); r1 += __shfl_xor(r1, mm); r2 += __shfl_xor(r2, mm);
      }
      float* row = ha + (size_t)(nb + k) * 68;
      row[lane] = h;
      if (lane == 0) {
        float hi = 1.f / (sqrtf(r0) + 1e-12f);
        row[64] = r1 * hi * ip0;
        row[65] = r2 * hi * ip1;
      }
    }
  }
}

// ---------------------------------------------------------------------------
// K2: xl (or xr) = ha @ W + b, stored bf16 HEAD-MAJOR: outp[n*256 + lane*4+j]
// holds head h=lane>>4, channels (lane&15)*4+j. W staged bf16 in LDS
// (identity layout since h*64+c == 4*lane+j). 4 nodes per wave.
// ---------------------------------------------------------------------------
__global__ __launch_bounds__(256) void k_lin(
    const float* __restrict__ ha, const float* __restrict__ W,
    const float* __restrict__ b, u16* __restrict__ outp)
{
  __shared__ u16 wl[GAT_IN * 256];  // 33.8 KB
  for (int m = threadIdx.x; m < GAT_IN * 256; m += 256) wl[m] = f2bf(W[m]);
  __syncthreads();
  const int lane = threadIdx.x & 63;
  const int gid = blockIdx.x * 4 + (threadIdx.x >> 6);
  float4 bv = *(const float4*)(b + lane * 4);

  for (int nb = gid * 4; nb < N_NODES; nb += 20000) {
    const float* r0 = ha + (size_t)nb * 68;
    const float* r1 = r0 + 68;
    const float* r2 = r1 + 68;
    const float* r3 = r2 + 68;
    float a00=0,a01=0,a02=0,a03=0, a10=0,a11=0,a12=0,a13=0;
    float a20=0,a21=0,a22=0,a23=0, a30=0,a31=0,a32=0,a33=0;
    #pragma unroll 2
    for (int i = 0; i < GAT_IN; ++i) {
      ushort4 wv = *(const ushort4*)&wl[i * 256 + lane * 4];
      float w0 = bf2f(wv.x), w1 = bf2f(wv.y), w2 = bf2f(wv.z), w3 = bf2f(wv.w);
      float h0 = r0[i], h1 = r1[i], h2 = r2[i], h3 = r3[i];
      a00 += h0*w0; a01 += h0*w1; a02 += h0*w2; a03 += h0*w3;
      a10 += h1*w0; a11 += h1*w1; a12 += h1*w2; a13 += h1*w3;
      a20 += h2*w0; a21 += h2*w1; a22 += h2*w2; a23 += h2*w3;
      a30 += h3*w0; a31 += h3*w1; a32 += h3*w2; a33 += h3*w3;
    }
    ushort4 o;
    o.x=f2bf(a00+bv.x); o.y=f2bf(a01+bv.y); o.z=f2bf(a02+bv.z); o.w=f2bf(a03+bv.w);
    *(ushort4*)(outp + (size_t)(nb+0)*256 + lane*4) = o;
    o.x=f2bf(a10+bv.x); o.y=f2bf(a11+bv.y); o.z=f2bf(a12+bv.z); o.w=f2bf(a13+bv.w);
    *(ushort4*)(outp + (size_t)(nb+1)*256 + lane*4) = o;
    o.x=f2bf(a20+bv.x); o.y=f2bf(a21+bv.y); o.z=f2bf(a22+bv.z); o.w=f2bf(a23+bv.w);
    *(ushort4*)(outp + (size_t)(nb+2)*256 + lane*4) = o;
    o.x=f2bf(a30+bv.x); o.y=f2bf(a31+bv.y); o.z=f2bf(a32+bv.z); o.w=f2bf(a33+bv.w);
    *(ushort4*)(outp + (size_t)(nb+3)*256 + lane*4) = o;
  }
}

// --------------------------- CSR construction ------------------------------
__global__ void k_hist(const void* __restrict__ ei, const int* __restrict__ flag_i,
                       int* __restrict__ deg) {
  int e = blockIdx.x * 256 + threadIdx.x;
  if (e >= N_EDGES) return;
  int d;
  if (*flag_i) d = (int)((const long long*)ei)[N_EDGES + e];
  else         d = ((const int*)ei)[N_EDGES + e];
  if ((unsigned)d < N_NODES) atomicAdd(&deg[d], 1);
}

__global__ __launch_bounds__(1024) void k_scan(
    const int* __restrict__ deg, int* __restrict__ off, int* __restrict__ cur)
{
  __shared__ int part[1024];
  const int t = threadIdx.x;
  const int CH = 49;  // 1024*49 = 50176 >= 50000
  int base = t * CH;
  int s = 0;
  for (int i = 0; i < CH; i++) { int id = base + i; if (id < N_NODES) s += deg[id]; }
  part[t] = s;
  __syncthreads();
  for (int d = 1; d < 1024; d <<= 1) {
    int v = part[t];
    int w = (t >= d) ? part[t - d] : 0;
    __syncthreads();
    part[t] = v + w;
    __syncthreads();
  }
  int pre = (t > 0) ? part[t - 1] : 0;
  for (int i = 0; i < CH; i++) {
    int id = base + i;
    if (id < N_NODES) { off[id] = pre; cur[id] = pre; pre += deg[id]; }
  }
  if (t == 1023) off[N_NODES] = part[1023];
}

__global__ void k_scatter(const void* __restrict__ ei, const int* __restrict__ flag_i,
                          int* __restrict__ cur, int* __restrict__ esrc) {
  int e = blockIdx.x * 256 + threadIdx.x;
  if (e >= N_EDGES) return;
  int s, d;
  if (*flag_i) {
    s = (int)((const long long*)ei)[e];
    d = (int)((const long long*)ei)[N_EDGES + e];
  } else {
    s = ((const int*)ei)[e];
    d = ((const int*)ei)[N_EDGES + e];
  }
  if ((unsigned)d >= N_NODES) return;
  if ((unsigned)s >= N_NODES) s = 0;
  int p = atomicAdd(&cur[d], 1);
  if ((unsigned)p < N_EDGES) esrc[p] = s;
}

// ---------------------------------------------------------------------------
// K5: per-dst-node online-softmax + head-mean + relu + classifier.
// One wave per node. Head-major fragments: lane = (h=lane>>4, c4=(lane&15)*4).
// Logit reduction: 4-step shfl within 16-lane head group. 2-stage pipeline
// on the edge gather. INLINE_XR=1: compute xr from ha with LDS-staged Wr
// (fallback when ws too small for the xrs buffer).
// ---------------------------------------------------------------------------
template <int INLINE_XR>
__global__ __launch_bounds__(256) void k_agg(
    const u16* __restrict__ xls, const u16* __restrict__ xrs,
    const float* __restrict__ ha, const float* __restrict__ Wr,
    const float* __restrict__ br,
    const int* __restrict__ esrc, const int* __restrict__ off,
    const float* __restrict__ att, const float* __restrict__ gbias,
    const float* __restrict__ wcls, const float* __restrict__ bcls,
    float* __restrict__ out)
{
  __shared__ u16 wr[INLINE_XR ? GAT_IN * 256 : 64];
  if (INLINE_XR) {
    for (int m = threadIdx.x; m < GAT_IN * 256; m += 256) wr[m] = f2bf(Wr[m]);
    __syncthreads();
  }
  const int lane = threadIdx.x & 63;
  const int n = blockIdx.x * 4 + (threadIdx.x >> 6);
  if (n >= N_NODES) return;

  const float4 av = *(const float4*)(att + lane * 4);  // att[h][c4..c4+3]

  float xr0, xr1, xr2, xr3;
  if (INLINE_XR) {
    float4 bv = *(const float4*)(br + lane * 4);
    xr0 = bv.x; xr1 = bv.y; xr2 = bv.z; xr3 = bv.w;
    const float* hrow = ha + (size_t)n * 68;
    for (int i = 0; i < GAT_IN; ++i) {
      ushort4 wv = *(const ushort4*)&wr[i * 256 + lane * 4];
      float hv = hrow[i];
      xr0 += hv * bf2f(wv.x); xr1 += hv * bf2f(wv.y);
      xr2 += hv * bf2f(wv.z); xr3 += hv * bf2f(wv.w);
    }
  } else {
    ushort4 q = *(const ushort4*)(xrs + (size_t)n * 256 + lane * 4);
    xr0 = bf2f(q.x); xr1 = bf2f(q.y); xr2 = bf2f(q.z); xr3 = bf2f(q.w);
  }

  int kb = off[n], ke = off[n + 1];
  if (kb < 0) kb = 0;
  if (ke > N_EDGES) ke = N_EDGES;
  int deg = ke - kb; if (deg < 0) deg = 0;

  float m_ = -1e30f, l_ = 0.f;
  float c0 = 0.f, c1 = 0.f, c2 = 0.f, c3 = 0.f;

  // source sequence: self, esrc[kb..ke)
  int s1 = (deg > 0) ? esrc[kb] : n;
  ushort4 xc = *(const ushort4*)(xls + (size_t)n * 256 + lane * 4);  // self
  for (int i = 0; i <= deg; ++i) {
    int s2 = (i + 2 <= deg) ? esrc[kb + i + 1] : n;                   // idx prefetch
    ushort4 xn = *(const ushort4*)(xls + (size_t)s1 * 256 + lane * 4); // row prefetch
    float x0 = bf2f(xc.x), x1 = bf2f(xc.y), x2 = bf2f(xc.z), x3 = bf2f(xc.w);
    float t0 = x0 + xr0, t1 = x1 + xr1, t2 = x2 + xr2, t3 = x3 + xr3;
    t0 = (t0 > 0.f) ? t0 : 0.2f * t0;
    t1 = (t1 > 0.f) ? t1 : 0.2f * t1;
    t2 = (t2 > 0.f) ? t2 : 0.2f * t2;
    t3 = (t3 > 0.f) ? t3 : 0.2f * t3;
    float g = av.x * t0 + av.y * t1 + av.z * t2 + av.w * t3;
    g += __shfl_xor(g, 1); g += __shfl_xor(g, 2);
    g += __shfl_xor(g, 4); g += __shfl_xor(g, 8);
    float nm = fmaxf(m_, g);
    float sc = __expf(m_ - nm), a = __expf(g - nm);
    l_ = l_ * sc + a;
    c0 = c0 * sc + a * x0; c1 = c1 * sc + a * x1;
    c2 = c2 * sc + a * x2; c3 = c3 * sc + a * x3;
    m_ = nm;
    xc = xn; s1 = s2;
  }

  // normalize per head, mean over heads (lanes xor 16/32), bias+relu
  float inv = 1.f / (l_ + 1e-16f);
  float v0 = c0 * inv, v1 = c1 * inv, v2 = c2 * inv, v3 = c3 * inv;
  v0 += __shfl_xor(v0, 16); v0 += __shfl_xor(v0, 32);
  v1 += __shfl_xor(v1, 16); v1 += __shfl_xor(v1, 32);
  v2 += __shfl_xor(v2, 16); v2 += __shfl_xor(v2, 32);
  v3 += __shfl_xor(v3, 16); v3 += __shfl_xor(v3, 32);
  const int g4 = (lane & 15) * 4;
  const int h = lane >> 4;
  float4 gb = *(const float4*)(gbias + g4);
  v0 = fmaxf(0.25f * v0 + gb.x, 0.f);
  v1 = fmaxf(0.25f * v1 + gb.y, 0.f);
  v2 = fmaxf(0.25f * v2 + gb.z, 0.f);
  v3 = fmaxf(0.25f * v3 + gb.w, 0.f);
  // classifier: lane (h,g) computes outputs h*4..h*4+3 partial over its 4 chans
  float4 w0 = *(const float4*)(wcls + (g4 + 0) * 16 + h * 4);
  float4 w1 = *(const float4*)(wcls + (g4 + 1) * 16 + h * 4);
  float4 w2 = *(const float4*)(wcls + (g4 + 2) * 16 + h * 4);
  float4 w3 = *(const float4*)(wcls + (g4 + 3) * 16 + h * 4);
  float o0 = v0 * w0.x + v1 * w1.x + v2 * w2.x + v3 * w3.x;
  float o1 = v0 * w0.y + v1 * w1.y + v2 * w2.y + v3 * w3.y;
  float o2 = v0 * w0.z + v1 * w1.z + v2 * w2.z + v3 * w3.z;
  float o3 = v0 * w0.w + v1 * w1.w + v2 * w2.w + v3 * w3.w;
  #pragma unroll
  for (int mm = 1; mm < 16; mm <<= 1) {
    o0 += __shfl_xor(o0, mm); o1 += __shfl_xor(o1, mm);
    o2 += __shfl_xor(o2, mm); o3 += __shfl_xor(o3, mm);
  }
  if ((lane & 15) == 0) {
    float4 bcv = *(const float4*)(bcls + h * 4);
    float4 ov;
    ov.x = o0 + bcv.x; ov.y = o1 + bcv.y; ov.z = o2 + bcv.z; ov.w = o3 + bcv.w;
    *(float4*)(out + (size_t)n * 16 + h * 4) = ov;
  }
}

// ---------------------------------------------------------------------------
extern "C" void kernel_launch(void* const* d_in, const int* in_sizes, int n_in,
                              void* d_out, int out_size, void* d_ws, size_t ws_size,
                              hipStream_t stream)
{
  const float* x     = (const float*)d_in[0];
  const void*  ei    = d_in[1];
  const float* Win   = (const float*)d_in[2];
  const float* bin   = (const float*)d_in[3];
  const float* proto = (const float*)d_in[4];
  const float* Wl    = (const float*)d_in[5];
  const float* bl    = (const float*)d_in[6];
  const float* Wr    = (const float*)d_in[7];
  const float* br    = (const float*)d_in[8];
  const float* att   = (const float*)d_in[9];
  const float* gbias = (const float*)d_in[10];
  const float* wcls  = (const float*)d_in[11];
  const float* bcls  = (const float*)d_in[12];
  float* out = (float*)d_out;

  char* p = (char*)d_ws;
  size_t used = 0;
  auto carve = [&](size_t bytes) {
    char* q = p + used;
    used += (bytes + 255) & ~(size_t)255;
    return (void*)q;
  };
  int* flag_i = (int*)carve(256);
  int* deg  = (int*)carve(N_NODES * 4);
  int* off  = (int*)carve((N_NODES + 1) * 4);
  int* cur  = (int*)carve(N_NODES * 4);
  int* esrc = (int*)carve(N_EDGES * 4);
  float* ha = (float*)carve((size_t)N_NODES * 68 * 4);
  u16* xls  = (u16*)carve((size_t)N_NODES * 256 * 2);
  size_t used_min = used + ((size_t)N_NODES * 256 * 2);
  u16* xrs  = (u16*)carve((size_t)N_NODES * 256 * 2);
  const bool full = ws_size >= used_min;  // room for xrs buffer?

  k_detect<<<196, 256, 0, stream>>>(ei, flag_i, deg);
  k_haug<<<1250, 256, 0, stream>>>(x, Win, bin, proto, ha);
  k_hist<<<3125, 256, 0, stream>>>(ei, flag_i, deg);
  k_lin<<<1250, 256, 0, stream>>>(ha, Wl, bl, xls);
  if (full) k_lin<<<1250, 256, 0, stream>>>(ha, Wr, br, xrs);
  k_scan<<<1, 1024, 0, stream>>>(deg, off, cur);
  k_scatter<<<3125, 256, 0, stream>>>(ei, flag_i, cur, esrc);
  if (full)
    k_agg<0><<<12500, 256, 0, stream>>>(xls, xrs, ha, Wr, br, esrc, off,
                                        att, gbias, wcls, bcls, out);
  else
    k_agg<1><<<12500, 256, 0, stream>>>(xls, xrs, ha, Wr, br, esrc, off,
                                        att, gbias, wcls, bcls, out);
}

// Round 5
// 527.158 us; speedup vs baseline: 1.9097x; 1.2401x over previous
//
#include <hip/hip_runtime.h>

#define N_NODES 50000
#define N_EDGES 800000
#define IN_DIM 256
#define HID 64
#define OUT_DIM 16
#define GAT_IN 66   // HID + N_PROTO

typedef unsigned short u16;
typedef unsigned int u32;
typedef __attribute__((ext_vector_type(8))) short s8v;   // 8 bf16 (4 VGPRs)
typedef __attribute__((ext_vector_type(4))) float f4v;   // MFMA accumulator

__device__ __forceinline__ float bf2f(u16 u) {
  union { u32 i; float f; } v; v.i = ((u32)u) << 16; return v.f;
}
__device__ __forceinline__ u16 f2bf(float f) {
  union { float f; u32 i; } v; v.f = f;
  u32 r = v.i + 0x7FFFu + ((v.i >> 16) & 1u);
  return (u16)(r >> 16);
}
// split fp32 -> hi (truncated bf16) + lo (rounded bf16); hi+lo ~ 17-bit mantissa
__device__ __forceinline__ void split8(const float* uu, s8v& ah, s8v& al) {
  #pragma unroll
  for (int j = 0; j < 8; ++j) {
    u32 bits = __float_as_uint(uu[j]);
    u16 hb = (u16)(bits >> 16);
    ah[j] = (short)hb;
    al[j] = (short)f2bf(uu[j] - bf2f(hb));
  }
}

// ---------------------------------------------------------------------------
// K0: zero deg[]; detect int dtype of edge_index (int64 vs int32).
// ---------------------------------------------------------------------------
__global__ void k_detect(const void* __restrict__ ei, int* __restrict__ flag_i,
                         int* __restrict__ deg) {
  int i = blockIdx.x * 256 + threadIdx.x;
  if (i < N_NODES) deg[i] = 0;
  if (blockIdx.x == 0 && threadIdx.x == 0) {
    const long long* e64 = (const long long*)ei;
    int ok = 1;
    for (int k = 0; k < 64; k++) {
      long long v = e64[k];
      if (v < 0 || v >= N_NODES) { ok = 0; break; }
    }
    *flag_i = ok;
  }
}

// ---------------------------------------------------------------------------
// K1 (MFMA): h = relu(x @ W_in + b_in); sem = cosine sim vs prototypes.
// Wave = one 16-node M-tile; 4 N-tiles (64 cols); K=256 in 8 steps of 32.
// A = x split hi/lo bf16 (2 MFMAs per tile-step => fp32-grade A precision).
// B = W_in bf16 staged in LDS as [s][t][lane][j] (32 KB), one ds_read_b128
// per tile-step. D layout: col=lane&15, row=(lane>>4)*4+reg.
// ---------------------------------------------------------------------------
__global__ __launch_bounds__(256) void k_haug(
    const float* __restrict__ x, const float* __restrict__ Win,
    const float* __restrict__ bin, const float* __restrict__ proto,
    float* __restrict__ ha)
{
  __shared__ u16 wb[8 * 4 * 64 * 8];  // 32 KB: [s][t][l][j] = Win[k][c]
  for (int m = threadIdx.x; m < 16384; m += 256) {
    int j = m & 7, l = (m >> 3) & 63, t = (m >> 9) & 3, s = m >> 11;
    int k = s * 32 + (l >> 4) * 8 + j;
    int c = t * 16 + (l & 15);
    wb[m] = f2bf(Win[k * 64 + c]);
  }
  __syncthreads();
  const int lane = threadIdx.x & 63;
  const int nb = blockIdx.x * 64 + (threadIdx.x >> 6) * 16;
  if (nb >= N_NODES) return;
  const int mrow = lane & 15, q = lane >> 4;

  f4v acc0 = {0.f,0.f,0.f,0.f}, acc1 = {0.f,0.f,0.f,0.f};
  f4v acc2 = {0.f,0.f,0.f,0.f}, acc3 = {0.f,0.f,0.f,0.f};
  const float* xrow = x + (size_t)(nb + mrow) * IN_DIM + q * 8;
  #pragma unroll 2
  for (int s = 0; s < 8; ++s) {
    float4 u0 = *(const float4*)(xrow + s * 32);
    float4 u1 = *(const float4*)(xrow + s * 32 + 4);
    float uu[8] = {u0.x, u0.y, u0.z, u0.w, u1.x, u1.y, u1.z, u1.w};
    s8v ah, al;
    split8(uu, ah, al);
    const u16* wp = &wb[s * 2048 + lane * 8];
    s8v b0 = *(const s8v*)(wp);
    s8v b1 = *(const s8v*)(wp + 512);
    s8v b2 = *(const s8v*)(wp + 1024);
    s8v b3 = *(const s8v*)(wp + 1536);
    acc0 = __builtin_amdgcn_mfma_f32_16x16x32_bf16(ah, b0, acc0, 0, 0, 0);
    acc0 = __builtin_amdgcn_mfma_f32_16x16x32_bf16(al, b0, acc0, 0, 0, 0);
    acc1 = __builtin_amdgcn_mfma_f32_16x16x32_bf16(ah, b1, acc1, 0, 0, 0);
    acc1 = __builtin_amdgcn_mfma_f32_16x16x32_bf16(al, b1, acc1, 0, 0, 0);
    acc2 = __builtin_amdgcn_mfma_f32_16x16x32_bf16(ah, b2, acc2, 0, 0, 0);
    acc2 = __builtin_amdgcn_mfma_f32_16x16x32_bf16(al, b2, acc2, 0, 0, 0);
    acc3 = __builtin_amdgcn_mfma_f32_16x16x32_bf16(ah, b3, acc3, 0, 0, 0);
    acc3 = __builtin_amdgcn_mfma_f32_16x16x32_bf16(al, b3, acc3, 0, 0, 0);
  }

  // epilogue: bias+relu, cosine sims, write ha rows
  float bt[4], p0t[4], p1t[4];
  #pragma unroll
  for (int t = 0; t < 4; ++t) {
    bt[t]  = bin[t * 16 + mrow];
    p0t[t] = proto[t * 16 + mrow];
    p1t[t] = proto[64 + t * 16 + mrow];
  }
  float np0 = 0.f, np1 = 0.f;
  #pragma unroll
  for (int t = 0; t < 4; ++t) { np0 += p0t[t] * p0t[t]; np1 += p1t[t] * p1t[t]; }
  #pragma unroll
  for (int mm = 1; mm < 16; mm <<= 1) {
    np0 += __shfl_xor(np0, mm); np1 += __shfl_xor(np1, mm);
  }
  const float ip0 = 1.f / (sqrtf(np0) + 1e-12f);
  const float ip1 = 1.f / (sqrtf(np1) + 1e-12f);

  float hcol[4][4];  // [t][r]
  #pragma unroll
  for (int r = 0; r < 4; ++r) {
    hcol[0][r] = fmaxf(acc0[r] + bt[0], 0.f);
    hcol[1][r] = fmaxf(acc1[r] + bt[1], 0.f);
    hcol[2][r] = fmaxf(acc2[r] + bt[2], 0.f);
    hcol[3][r] = fmaxf(acc3[r] + bt[3], 0.f);
  }
  #pragma unroll
  for (int r = 0; r < 4; ++r) {
    float r0 = 0.f, r1 = 0.f, r2 = 0.f;
    #pragma unroll
    for (int t = 0; t < 4; ++t) {
      float h = hcol[t][r];
      r0 += h * h; r1 += h * p0t[t]; r2 += h * p1t[t];
    }
    #pragma unroll
    for (int mm = 1; mm < 16; mm <<= 1) {
      r0 += __shfl_xor(r0, mm); r1 += __shfl_xor(r1, mm); r2 += __shfl_xor(r2, mm);
    }
    float* row = ha + (size_t)(nb + q * 4 + r) * 68;
    #pragma unroll
    for (int t = 0; t < 4; ++t) row[t * 16 + mrow] = hcol[t][r];
    if (mrow == 0) {
      float hi = 1.f / (sqrtf(r0) + 1e-12f);
      row[64] = r1 * hi * ip0;
      row[65] = r2 * hi * ip1;
    }
  }
}

// ---------------------------------------------------------------------------
// K2 (MFMA): xl (or xr) = ha @ W + b  -> bf16 [n][256] (col j = h*64+c).
// Wave = one 16-node M-tile; 16 N-tiles; K=66 padded to 96 (3 steps of 32).
// A = ha split hi/lo bf16; B = W bf16 staged in LDS (48 KB), rows >=66 zero.
// ---------------------------------------------------------------------------
__global__ __launch_bounds__(256) void k_lin(
    const float* __restrict__ ha, const float* __restrict__ W,
    const float* __restrict__ b, u16* __restrict__ outp)
{
  __shared__ u16 wl[3 * 16 * 64 * 8];  // 48 KB: [s][t][l][j] = W[k][j2]
  for (int m = threadIdx.x; m < 24576; m += 256) {
    int j = m & 7, l = (m >> 3) & 63, t = (m >> 9) & 15, s = m >> 13;
    int k = s * 32 + (l >> 4) * 8 + j;
    int j2 = t * 16 + (l & 15);
    wl[m] = (k < GAT_IN) ? f2bf(W[k * 256 + j2]) : (u16)0;
  }
  __syncthreads();
  const int lane = threadIdx.x & 63;
  const int nb = blockIdx.x * 64 + (threadIdx.x >> 6) * 16;
  if (nb >= N_NODES) return;
  const int mrow = lane & 15, q = lane >> 4;

  f4v acc[16];
  #pragma unroll
  for (int t = 0; t < 16; ++t) acc[t] = (f4v){0.f, 0.f, 0.f, 0.f};

  const float* row = ha + (size_t)(nb + mrow) * 68;
  #pragma unroll
  for (int s = 0; s < 3; ++s) {
    float uu[8];
    if (s < 2) {
      float4 u0 = *(const float4*)(row + s * 32 + q * 8);
      float4 u1 = *(const float4*)(row + s * 32 + q * 8 + 4);
      uu[0]=u0.x; uu[1]=u0.y; uu[2]=u0.z; uu[3]=u0.w;
      uu[4]=u1.x; uu[5]=u1.y; uu[6]=u1.z; uu[7]=u1.w;
    } else {
      #pragma unroll
      for (int j = 0; j < 8; ++j) uu[j] = 0.f;
      if (q == 0) { uu[0] = row[64]; uu[1] = row[65]; }  // sem channels (k=64,65)
    }
    s8v ah, al;
    split8(uu, ah, al);
    const u16* wp = &wl[s * 8192 + lane * 8];
    #pragma unroll
    for (int t = 0; t < 16; ++t) {
      s8v bv = *(const s8v*)(wp + t * 512);
      acc[t] = __builtin_amdgcn_mfma_f32_16x16x32_bf16(ah, bv, acc[t], 0, 0, 0);
      acc[t] = __builtin_amdgcn_mfma_f32_16x16x32_bf16(al, bv, acc[t], 0, 0, 0);
    }
  }

  #pragma unroll
  for (int t = 0; t < 16; ++t) {
    float bc = b[t * 16 + mrow];
    #pragma unroll
    for (int r = 0; r < 4; ++r) {
      outp[(size_t)(nb + q * 4 + r) * 256 + t * 16 + mrow] = f2bf(acc[t][r] + bc);
    }
  }
}

// --------------------------- CSR construction ------------------------------
__global__ void k_hist(const void* __restrict__ ei, const int* __restrict__ flag_i,
                       int* __restrict__ deg) {
  int e = blockIdx.x * 256 + threadIdx.x;
  if (e >= N_EDGES) return;
  int d;
  if (*flag_i) d = (int)((const long long*)ei)[N_EDGES + e];
  else         d = ((const int*)ei)[N_EDGES + e];
  if ((unsigned)d < N_NODES) atomicAdd(&deg[d], 1);
}

__global__ __launch_bounds__(1024) void k_scan(
    const int* __restrict__ deg, int* __restrict__ off, int* __restrict__ cur)
{
  __shared__ int part[1024];
  const int t = threadIdx.x;
  const int CH = 49;  // 1024*49 = 50176 >= 50000
  int base = t * CH;
  int s = 0;
  for (int i = 0; i < CH; i++) { int id = base + i; if (id < N_NODES) s += deg[id]; }
  part[t] = s;
  __syncthreads();
  for (int d = 1; d < 1024; d <<= 1) {
    int v = part[t];
    int w = (t >= d) ? part[t - d] : 0;
    __syncthreads();
    part[t] = v + w;
    __syncthreads();
  }
  int pre = (t > 0) ? part[t - 1] : 0;
  for (int i = 0; i < CH; i++) {
    int id = base + i;
    if (id < N_NODES) { off[id] = pre; cur[id] = pre; pre += deg[id]; }
  }
  if (t == 1023) off[N_NODES] = part[1023];
}

__global__ void k_scatter(const void* __restrict__ ei, const int* __restrict__ flag_i,
                          int* __restrict__ cur, int* __restrict__ esrc) {
  int e = blockIdx.x * 256 + threadIdx.x;
  if (e >= N_EDGES) return;
  int s, d;
  if (*flag_i) {
    s = (int)((const long long*)ei)[e];
    d = (int)((const long long*)ei)[N_EDGES + e];
  } else {
    s = ((const int*)ei)[e];
    d = ((const int*)ei)[N_EDGES + e];
  }
  if ((unsigned)d >= N_NODES) return;
  if ((unsigned)s >= N_NODES) s = 0;
  int p = atomicAdd(&cur[d], 1);
  if ((unsigned)p < N_EDGES) esrc[p] = s;
}

// ---------------------------------------------------------------------------
// K5: per-dst-node online-softmax + head-mean + relu + classifier.
// One wave per node. Head-major fragments: lane = (h=lane>>4, c4=(lane&15)*4).
// ---------------------------------------------------------------------------
template <int INLINE_XR>
__global__ __launch_bounds__(256) void k_agg(
    const u16* __restrict__ xls, const u16* __restrict__ xrs,
    const float* __restrict__ ha, const float* __restrict__ Wr,
    const float* __restrict__ br,
    const int* __restrict__ esrc, const int* __restrict__ off,
    const float* __restrict__ att, const float* __restrict__ gbias,
    const float* __restrict__ wcls, const float* __restrict__ bcls,
    float* __restrict__ out)
{
  __shared__ u16 wr[INLINE_XR ? GAT_IN * 256 : 64];
  if (INLINE_XR) {
    for (int m = threadIdx.x; m < GAT_IN * 256; m += 256) wr[m] = f2bf(Wr[m]);
    __syncthreads();
  }
  const int lane = threadIdx.x & 63;
  const int n = blockIdx.x * 4 + (threadIdx.x >> 6);
  if (n >= N_NODES) return;

  const float4 av = *(const float4*)(att + lane * 4);

  float xr0, xr1, xr2, xr3;
  if (INLINE_XR) {
    float4 bv = *(const float4*)(br + lane * 4);
    xr0 = bv.x; xr1 = bv.y; xr2 = bv.z; xr3 = bv.w;
    const float* hrow = ha + (size_t)n * 68;
    for (int i = 0; i < GAT_IN; ++i) {
      ushort4 wv = *(const ushort4*)&wr[i * 256 + lane * 4];
      float hv = hrow[i];
      xr0 += hv * bf2f(wv.x); xr1 += hv * bf2f(wv.y);
      xr2 += hv * bf2f(wv.z); xr3 += hv * bf2f(wv.w);
    }
  } else {
    ushort4 qv = *(const ushort4*)(xrs + (size_t)n * 256 + lane * 4);
    xr0 = bf2f(qv.x); xr1 = bf2f(qv.y); xr2 = bf2f(qv.z); xr3 = bf2f(qv.w);
  }

  int kb = off[n], ke = off[n + 1];
  if (kb < 0) kb = 0;
  if (ke > N_EDGES) ke = N_EDGES;
  int deg = ke - kb; if (deg < 0) deg = 0;

  float m_ = -1e30f, l_ = 0.f;
  float c0 = 0.f, c1 = 0.f, c2 = 0.f, c3 = 0.f;

  int s1 = (deg > 0) ? esrc[kb] : n;
  ushort4 xc = *(const ushort4*)(xls + (size_t)n * 256 + lane * 4);  // self
  for (int i = 0; i <= deg; ++i) {
    int s2 = (i + 2 <= deg) ? esrc[kb + i + 1] : n;
    ushort4 xn = *(const ushort4*)(xls + (size_t)s1 * 256 + lane * 4);
    float x0 = bf2f(xc.x), x1 = bf2f(xc.y), x2 = bf2f(xc.z), x3 = bf2f(xc.w);
    float t0 = x0 + xr0, t1 = x1 + xr1, t2 = x2 + xr2, t3 = x3 + xr3;
    t0 = (t0 > 0.f) ? t0 : 0.2f * t0;
    t1 = (t1 > 0.f) ? t1 : 0.2f * t1;
    t2 = (t2 > 0.f) ? t2 : 0.2f * t2;
    t3 = (t3 > 0.f) ? t3 : 0.2f * t3;
    float g = av.x * t0 + av.y * t1 + av.z * t2 + av.w * t3;
    g += __shfl_xor(g, 1); g += __shfl_xor(g, 2);
    g += __shfl_xor(g, 4); g += __shfl_xor(g, 8);
    float nm = fmaxf(m_, g);
    float sc = __expf(m_ - nm), a = __expf(g - nm);
    l_ = l_ * sc + a;
    c0 = c0 * sc + a * x0; c1 = c1 * sc + a * x1;
    c2 = c2 * sc + a * x2; c3 = c3 * sc + a * x3;
    m_ = nm;
    xc = xn; s1 = s2;
  }

  float inv = 1.f / (l_ + 1e-16f);
  float v0 = c0 * inv, v1 = c1 * inv, v2 = c2 * inv, v3 = c3 * inv;
  v0 += __shfl_xor(v0, 16); v0 += __shfl_xor(v0, 32);
  v1 += __shfl_xor(v1, 16); v1 += __shfl_xor(v1, 32);
  v2 += __shfl_xor(v2, 16); v2 += __shfl_xor(v2, 32);
  v3 += __shfl_xor(v3, 16); v3 += __shfl_xor(v3, 32);
  const int g4 = (lane & 15) * 4;
  const int h = lane >> 4;
  float4 gb = *(const float4*)(gbias + g4);
  v0 = fmaxf(0.25f * v0 + gb.x, 0.f);
  v1 = fmaxf(0.25f * v1 + gb.y, 0.f);
  v2 = fmaxf(0.25f * v2 + gb.z, 0.f);
  v3 = fmaxf(0.25f * v3 + gb.w, 0.f);
  float4 w0 = *(const float4*)(wcls + (g4 + 0) * 16 + h * 4);
  float4 w1 = *(const float4*)(wcls + (g4 + 1) * 16 + h * 4);
  float4 w2 = *(const float4*)(wcls + (g4 + 2) * 16 + h * 4);
  float4 w3 = *(const float4*)(wcls + (g4 + 3) * 16 + h * 4);
  float o0 = v0 * w0.x + v1 * w1.x + v2 * w2.x + v3 * w3.x;
  float o1 = v0 * w0.y + v1 * w1.y + v2 * w2.y + v3 * w3.y;
  float o2 = v0 * w0.z + v1 * w1.z + v2 * w2.z + v3 * w3.z;
  float o3 = v0 * w0.w + v1 * w1.w + v2 * w2.w + v3 * w3.w;
  #pragma unroll
  for (int mm = 1; mm < 16; mm <<= 1) {
    o0 += __shfl_xor(o0, mm); o1 += __shfl_xor(o1, mm);
    o2 += __shfl_xor(o2, mm); o3 += __shfl_xor(o3, mm);
  }
  if ((lane & 15) == 0) {
    float4 bcv = *(const float4*)(bcls + h * 4);
    float4 ov;
    ov.x = o0 + bcv.x; ov.y = o1 + bcv.y; ov.z = o2 + bcv.z; ov.w = o3 + bcv.w;
    *(float4*)(out + (size_t)n * 16 + h * 4) = ov;
  }
}

// ---------------------------------------------------------------------------
extern "C" void kernel_launch(void* const* d_in, const int* in_sizes, int n_in,
                              void* d_out, int out_size, void* d_ws, size_t ws_size,
                              hipStream_t stream)
{
  const float* x     = (const float*)d_in[0];
  const void*  ei    = d_in[1];
  const float* Win   = (const float*)d_in[2];
  const float* bin   = (const float*)d_in[3];
  const float* proto = (const float*)d_in[4];
  const float* Wl    = (const float*)d_in[5];
  const float* bl    = (const float*)d_in[6];
  const float* Wr    = (const float*)d_in[7];
  const float* br    = (const float*)d_in[8];
  const float* att   = (const float*)d_in[9];
  const float* gbias = (const float*)d_in[10];
  const float* wcls  = (const float*)d_in[11];
  const float* bcls  = (const float*)d_in[12];
  float* out = (float*)d_out;

  char* p = (char*)d_ws;
  size_t used = 0;
  auto carve = [&](size_t bytes) {
    char* q = p + used;
    used += (bytes + 255) & ~(size_t)255;
    return (void*)q;
  };
  int* flag_i = (int*)carve(256);
  int* deg  = (int*)carve(N_NODES * 4);
  int* off  = (int*)carve((N_NODES + 1) * 4);
  int* cur  = (int*)carve(N_NODES * 4);
  int* esrc = (int*)carve(N_EDGES * 4);
  float* ha = (float*)carve((size_t)N_NODES * 68 * 4 + 512);  // +pad
  u16* xls  = (u16*)carve((size_t)N_NODES * 256 * 2);
  size_t used_min = used + ((size_t)N_NODES * 256 * 2);
  u16* xrs  = (u16*)carve((size_t)N_NODES * 256 * 2);
  const bool full = ws_size >= used_min;

  k_detect<<<196, 256, 0, stream>>>(ei, flag_i, deg);
  k_haug<<<782, 256, 0, stream>>>(x, Win, bin, proto, ha);
  k_hist<<<3125, 256, 0, stream>>>(ei, flag_i, deg);
  k_lin<<<782, 256, 0, stream>>>(ha, Wl, bl, xls);
  if (full) k_lin<<<782, 256, 0, stream>>>(ha, Wr, br, xrs);
  k_scan<<<1, 1024, 0, stream>>>(deg, off, cur);
  k_scatter<<<3125, 256, 0, stream>>>(ei, flag_i, cur, esrc);
  if (full)
    k_agg<0><<<12500, 256, 0, stream>>>(xls, xrs, ha, Wr, br, esrc, off,
                                        att, gbias, wcls, bcls, out);
  else
    k_agg<1><<<12500, 256, 0, stream>>>(xls, xrs, ha, Wr, br, esrc, off,
                                        att, gbias, wcls, bcls, out);
}

// Round 6
// 411.668 us; speedup vs baseline: 2.4455x; 1.2805x over previous
//
#include <hip/hip_runtime.h>

#define N_NODES 50000
#define N_EDGES 800000
#define IN_DIM 256
#define HID 64
#define OUT_DIM 16
#define GAT_IN 66   // HID + N_PROTO
#define NB_SCAN 196 // 196*256 = 50176 >= N_NODES

typedef unsigned short u16;
typedef unsigned int u32;
typedef __attribute__((ext_vector_type(8))) short s8v;   // 8 bf16 (4 VGPRs)
typedef __attribute__((ext_vector_type(4))) float f4v;   // MFMA accumulator

__device__ __forceinline__ float bf2f(u16 u) {
  union { u32 i; float f; } v; v.i = ((u32)u) << 16; return v.f;
}
__device__ __forceinline__ u16 f2bf(float f) {
  union { float f; u32 i; } v; v.f = f;
  u32 r = v.i + 0x7FFFu + ((v.i >> 16) & 1u);
  return (u16)(r >> 16);
}
// split fp32 -> hi (truncated bf16) + lo (rounded bf16); hi+lo ~ 17-bit mantissa
__device__ __forceinline__ void split8(const float* uu, s8v& ah, s8v& al) {
  #pragma unroll
  for (int j = 0; j < 8; ++j) {
    u32 bits = __float_as_uint(uu[j]);
    u16 hb = (u16)(bits >> 16);
    ah[j] = (short)hb;
    al[j] = (short)f2bf(uu[j] - bf2f(hb));
  }
}

// ---------------------------------------------------------------------------
// K0: zero deg[]; detect int dtype of edge_index (int64 vs int32).
// ---------------------------------------------------------------------------
__global__ void k_detect(const void* __restrict__ ei, int* __restrict__ flag_i,
                         int* __restrict__ deg) {
  int i = blockIdx.x * 256 + threadIdx.x;
  if (i < N_NODES) deg[i] = 0;
  if (blockIdx.x == 0 && threadIdx.x == 0) {
    const long long* e64 = (const long long*)ei;
    int ok = 1;
    for (int k = 0; k < 64; k++) {
      long long v = e64[k];
      if (v < 0 || v >= N_NODES) { ok = 0; break; }
    }
    *flag_i = ok;
  }
}

// ---------------------------------------------------------------------------
// K1 (MFMA): h = relu(x @ W_in + b_in); sem = cosine sim vs prototypes.
// ---------------------------------------------------------------------------
__global__ __launch_bounds__(256) void k_haug(
    const float* __restrict__ x, const float* __restrict__ Win,
    const float* __restrict__ bin, const float* __restrict__ proto,
    float* __restrict__ ha)
{
  __shared__ u16 wb[8 * 4 * 64 * 8];  // 32 KB: [s][t][l][j] = Win[k][c]
  for (int m = threadIdx.x; m < 16384; m += 256) {
    int j = m & 7, l = (m >> 3) & 63, t = (m >> 9) & 3, s = m >> 11;
    int k = s * 32 + (l >> 4) * 8 + j;
    int c = t * 16 + (l & 15);
    wb[m] = f2bf(Win[k * 64 + c]);
  }
  __syncthreads();
  const int lane = threadIdx.x & 63;
  const int nb = blockIdx.x * 64 + (threadIdx.x >> 6) * 16;
  if (nb >= N_NODES) return;
  const int mrow = lane & 15, q = lane >> 4;

  f4v acc0 = {0.f,0.f,0.f,0.f}, acc1 = {0.f,0.f,0.f,0.f};
  f4v acc2 = {0.f,0.f,0.f,0.f}, acc3 = {0.f,0.f,0.f,0.f};
  const float* xrow = x + (size_t)(nb + mrow) * IN_DIM + q * 8;
  #pragma unroll 2
  for (int s = 0; s < 8; ++s) {
    float4 u0 = *(const float4*)(xrow + s * 32);
    float4 u1 = *(const float4*)(xrow + s * 32 + 4);
    float uu[8] = {u0.x, u0.y, u0.z, u0.w, u1.x, u1.y, u1.z, u1.w};
    s8v ah, al;
    split8(uu, ah, al);
    const u16* wp = &wb[s * 2048 + lane * 8];
    s8v b0 = *(const s8v*)(wp);
    s8v b1 = *(const s8v*)(wp + 512);
    s8v b2 = *(const s8v*)(wp + 1024);
    s8v b3 = *(const s8v*)(wp + 1536);
    acc0 = __builtin_amdgcn_mfma_f32_16x16x32_bf16(ah, b0, acc0, 0, 0, 0);
    acc0 = __builtin_amdgcn_mfma_f32_16x16x32_bf16(al, b0, acc0, 0, 0, 0);
    acc1 = __builtin_amdgcn_mfma_f32_16x16x32_bf16(ah, b1, acc1, 0, 0, 0);
    acc1 = __builtin_amdgcn_mfma_f32_16x16x32_bf16(al, b1, acc1, 0, 0, 0);
    acc2 = __builtin_amdgcn_mfma_f32_16x16x32_bf16(ah, b2, acc2, 0, 0, 0);
    acc2 = __builtin_amdgcn_mfma_f32_16x16x32_bf16(al, b2, acc2, 0, 0, 0);
    acc3 = __builtin_amdgcn_mfma_f32_16x16x32_bf16(ah, b3, acc3, 0, 0, 0);
    acc3 = __builtin_amdgcn_mfma_f32_16x16x32_bf16(al, b3, acc3, 0, 0, 0);
  }

  float bt[4], p0t[4], p1t[4];
  #pragma unroll
  for (int t = 0; t < 4; ++t) {
    bt[t]  = bin[t * 16 + mrow];
    p0t[t] = proto[t * 16 + mrow];
    p1t[t] = proto[64 + t * 16 + mrow];
  }
  float np0 = 0.f, np1 = 0.f;
  #pragma unroll
  for (int t = 0; t < 4; ++t) { np0 += p0t[t] * p0t[t]; np1 += p1t[t] * p1t[t]; }
  #pragma unroll
  for (int mm = 1; mm < 16; mm <<= 1) {
    np0 += __shfl_xor(np0, mm); np1 += __shfl_xor(np1, mm);
  }
  const float ip0 = 1.f / (sqrtf(np0) + 1e-12f);
  const float ip1 = 1.f / (sqrtf(np1) + 1e-12f);

  float hcol[4][4];  // [t][r]
  #pragma unroll
  for (int r = 0; r < 4; ++r) {
    hcol[0][r] = fmaxf(acc0[r] + bt[0], 0.f);
    hcol[1][r] = fmaxf(acc1[r] + bt[1], 0.f);
    hcol[2][r] = fmaxf(acc2[r] + bt[2], 0.f);
    hcol[3][r] = fmaxf(acc3[r] + bt[3], 0.f);
  }
  #pragma unroll
  for (int r = 0; r < 4; ++r) {
    float r0 = 0.f, r1 = 0.f, r2 = 0.f;
    #pragma unroll
    for (int t = 0; t < 4; ++t) {
      float h = hcol[t][r];
      r0 += h * h; r1 += h * p0t[t]; r2 += h * p1t[t];
    }
    #pragma unroll
    for (int mm = 1; mm < 16; mm <<= 1) {
      r0 += __shfl_xor(r0, mm); r1 += __shfl_xor(r1, mm); r2 += __shfl_xor(r2, mm);
    }
    float* row = ha + (size_t)(nb + q * 4 + r) * 68;
    #pragma unroll
    for (int t = 0; t < 4; ++t) row[t * 16 + mrow] = hcol[t][r];
    if (mrow == 0) {
      float hi = 1.f / (sqrtf(r0) + 1e-12f);
      row[64] = r1 * hi * ip0;
      row[65] = r2 * hi * ip1;
    }
  }
}

// ---------------------------------------------------------------------------
// K2 (MFMA): xl (or xr) = ha @ W + b  -> bf16 [n][256] (col j = h*64+c).
// ---------------------------------------------------------------------------
__global__ __launch_bounds__(256) void k_lin(
    const float* __restrict__ ha, const float* __restrict__ W,
    const float* __restrict__ b, u16* __restrict__ outp)
{
  __shared__ u16 wl[3 * 16 * 64 * 8];  // 48 KB
  for (int m = threadIdx.x; m < 24576; m += 256) {
    int j = m & 7, l = (m >> 3) & 63, t = (m >> 9) & 15, s = m >> 13;
    int k = s * 32 + (l >> 4) * 8 + j;
    int j2 = t * 16 + (l & 15);
    wl[m] = (k < GAT_IN) ? f2bf(W[k * 256 + j2]) : (u16)0;
  }
  __syncthreads();
  const int lane = threadIdx.x & 63;
  const int nb = blockIdx.x * 64 + (threadIdx.x >> 6) * 16;
  if (nb >= N_NODES) return;
  const int mrow = lane & 15, q = lane >> 4;

  f4v acc[16];
  #pragma unroll
  for (int t = 0; t < 16; ++t) acc[t] = (f4v){0.f, 0.f, 0.f, 0.f};

  const float* row = ha + (size_t)(nb + mrow) * 68;
  #pragma unroll
  for (int s = 0; s < 3; ++s) {
    float uu[8];
    if (s < 2) {
      float4 u0 = *(const float4*)(row + s * 32 + q * 8);
      float4 u1 = *(const float4*)(row + s * 32 + q * 8 + 4);
      uu[0]=u0.x; uu[1]=u0.y; uu[2]=u0.z; uu[3]=u0.w;
      uu[4]=u1.x; uu[5]=u1.y; uu[6]=u1.z; uu[7]=u1.w;
    } else {
      #pragma unroll
      for (int j = 0; j < 8; ++j) uu[j] = 0.f;
      if (q == 0) { uu[0] = row[64]; uu[1] = row[65]; }
    }
    s8v ah, al;
    split8(uu, ah, al);
    const u16* wp = &wl[s * 8192 + lane * 8];
    #pragma unroll
    for (int t = 0; t < 16; ++t) {
      s8v bv = *(const s8v*)(wp + t * 512);
      acc[t] = __builtin_amdgcn_mfma_f32_16x16x32_bf16(ah, bv, acc[t], 0, 0, 0);
      acc[t] = __builtin_amdgcn_mfma_f32_16x16x32_bf16(al, bv, acc[t], 0, 0, 0);
    }
  }

  #pragma unroll
  for (int t = 0; t < 16; ++t) {
    float bc = b[t * 16 + mrow];
    #pragma unroll
    for (int r = 0; r < 4; ++r) {
      outp[(size_t)(nb + q * 4 + r) * 256 + t * 16 + mrow] = f2bf(acc[t][r] + bc);
    }
  }
}

// --------------------------- CSR construction ------------------------------
__global__ void k_hist(const void* __restrict__ ei, const int* __restrict__ flag_i,
                       int* __restrict__ deg) {
  int e = blockIdx.x * 256 + threadIdx.x;
  if (e >= N_EDGES) return;
  int d;
  if (*flag_i) d = (int)((const long long*)ei)[N_EDGES + e];
  else         d = ((const int*)ei)[N_EDGES + e];
  if ((unsigned)d < N_NODES) atomicAdd(&deg[d], 1);
}

// 3-phase multi-block exclusive scan of deg[] -> off[], cur[]
__global__ __launch_bounds__(256) void k_scan_a(
    const int* __restrict__ deg, int* __restrict__ bsum)
{
  int i = blockIdx.x * 256 + threadIdx.x;
  int v = (i < N_NODES) ? deg[i] : 0;
  #pragma unroll
  for (int d = 1; d < 64; d <<= 1) v += __shfl_xor(v, d);
  __shared__ int wsum[4];
  if ((threadIdx.x & 63) == 0) wsum[threadIdx.x >> 6] = v;
  __syncthreads();
  if (threadIdx.x == 0)
    bsum[blockIdx.x] = wsum[0] + wsum[1] + wsum[2] + wsum[3];
}

__global__ __launch_bounds__(256) void k_scan_b(
    const int* __restrict__ bsum, int* __restrict__ boff)
{
  const int t = threadIdx.x;
  const int lane = t & 63;
  int v = (t < NB_SCAN) ? bsum[t] : 0;
  int inc = v;
  #pragma unroll
  for (int d = 1; d < 64; d <<= 1) {
    int sv = __shfl_up(inc, d);
    if (lane >= d) inc += sv;
  }
  __shared__ int wtot[4];
  if (lane == 63) wtot[t >> 6] = inc;
  __syncthreads();
  int add = 0;
  for (int w = 0; w < (t >> 6); ++w) add += wtot[w];
  if (t < NB_SCAN) boff[t] = add + inc - v;  // exclusive
}

__global__ __launch_bounds__(256) void k_scan_c(
    const int* __restrict__ deg, const int* __restrict__ boff,
    int* __restrict__ off, int* __restrict__ cur)
{
  const int t = threadIdx.x;
  const int lane = t & 63;
  int i = blockIdx.x * 256 + t;
  int v = (i < N_NODES) ? deg[i] : 0;
  int inc = v;
  #pragma unroll
  for (int d = 1; d < 64; d <<= 1) {
    int sv = __shfl_up(inc, d);
    if (lane >= d) inc += sv;
  }
  __shared__ int wtot[4];
  if (lane == 63) wtot[t >> 6] = inc;
  __syncthreads();
  int add = boff[blockIdx.x];
  for (int w = 0; w < (t >> 6); ++w) add += wtot[w];
  int ex = add + inc - v;
  if (i < N_NODES) { off[i] = ex; cur[i] = ex; }
  if (i == N_NODES - 1) off[N_NODES] = ex + v;
}

__global__ void k_scatter(const void* __restrict__ ei, const int* __restrict__ flag_i,
                          int* __restrict__ cur, int* __restrict__ esrc) {
  int e = blockIdx.x * 256 + threadIdx.x;
  if (e >= N_EDGES) return;
  int s, d;
  if (*flag_i) {
    s = (int)((const long long*)ei)[e];
    d = (int)((const long long*)ei)[N_EDGES + e];
  } else {
    s = ((const int*)ei)[e];
    d = ((const int*)ei)[N_EDGES + e];
  }
  if ((unsigned)d >= N_NODES) return;
  if ((unsigned)s >= N_NODES) s = 0;
  int p = atomicAdd(&cur[d], 1);
  if ((unsigned)p < N_EDGES) esrc[p] = s;
}

// ---------------------------------------------------------------------------
// K5: per-dst-node online-softmax + head-mean + relu + classifier.
// ---------------------------------------------------------------------------
template <int INLINE_XR>
__global__ __launch_bounds__(256) void k_agg(
    const u16* __restrict__ xls, const u16* __restrict__ xrs,
    const float* __restrict__ ha, const float* __restrict__ Wr,
    const float* __restrict__ br,
    const int* __restrict__ esrc, const int* __restrict__ off,
    const float* __restrict__ att, const float* __restrict__ gbias,
    const float* __restrict__ wcls, const float* __restrict__ bcls,
    float* __restrict__ out)
{
  __shared__ u16 wr[INLINE_XR ? GAT_IN * 256 : 64];
  if (INLINE_XR) {
    for (int m = threadIdx.x; m < GAT_IN * 256; m += 256) wr[m] = f2bf(Wr[m]);
    __syncthreads();
  }
  const int lane = threadIdx.x & 63;
  const int n = blockIdx.x * 4 + (threadIdx.x >> 6);
  if (n >= N_NODES) return;

  const float4 av = *(const float4*)(att + lane * 4);

  float xr0, xr1, xr2, xr3;
  if (INLINE_XR) {
    float4 bv = *(const float4*)(br + lane * 4);
    xr0 = bv.x; xr1 = bv.y; xr2 = bv.z; xr3 = bv.w;
    const float* hrow = ha + (size_t)n * 68;
    for (int i = 0; i < GAT_IN; ++i) {
      ushort4 wv = *(const ushort4*)&wr[i * 256 + lane * 4];
      float hv = hrow[i];
      xr0 += hv * bf2f(wv.x); xr1 += hv * bf2f(wv.y);
      xr2 += hv * bf2f(wv.z); xr3 += hv * bf2f(wv.w);
    }
  } else {
    ushort4 qv = *(const ushort4*)(xrs + (size_t)n * 256 + lane * 4);
    xr0 = bf2f(qv.x); xr1 = bf2f(qv.y); xr2 = bf2f(qv.z); xr3 = bf2f(qv.w);
  }

  int kb = off[n], ke = off[n + 1];
  if (kb < 0) kb = 0;
  if (ke > N_EDGES) ke = N_EDGES;
  int deg = ke - kb; if (deg < 0) deg = 0;

  float m_ = -1e30f, l_ = 0.f;
  float c0 = 0.f, c1 = 0.f, c2 = 0.f, c3 = 0.f;

  int s1 = (deg > 0) ? esrc[kb] : n;
  ushort4 xc = *(const ushort4*)(xls + (size_t)n * 256 + lane * 4);  // self
  for (int i = 0; i <= deg; ++i) {
    int s2 = (i + 2 <= deg) ? esrc[kb + i + 1] : n;
    ushort4 xn = *(const ushort4*)(xls + (size_t)s1 * 256 + lane * 4);
    float x0 = bf2f(xc.x), x1 = bf2f(xc.y), x2 = bf2f(xc.z), x3 = bf2f(xc.w);
    float t0 = x0 + xr0, t1 = x1 + xr1, t2 = x2 + xr2, t3 = x3 + xr3;
    t0 = (t0 > 0.f) ? t0 : 0.2f * t0;
    t1 = (t1 > 0.f) ? t1 : 0.2f * t1;
    t2 = (t2 > 0.f) ? t2 : 0.2f * t2;
    t3 = (t3 > 0.f) ? t3 : 0.2f * t3;
    float g = av.x * t0 + av.y * t1 + av.z * t2 + av.w * t3;
    g += __shfl_xor(g, 1); g += __shfl_xor(g, 2);
    g += __shfl_xor(g, 4); g += __shfl_xor(g, 8);
    float nm = fmaxf(m_, g);
    float sc = __expf(m_ - nm), a = __expf(g - nm);
    l_ = l_ * sc + a;
    c0 = c0 * sc + a * x0; c1 = c1 * sc + a * x1;
    c2 = c2 * sc + a * x2; c3 = c3 * sc + a * x3;
    m_ = nm;
    xc = xn; s1 = s2;
  }

  float inv = 1.f / (l_ + 1e-16f);
  float v0 = c0 * inv, v1 = c1 * inv, v2 = c2 * inv, v3 = c3 * inv;
  v0 += __shfl_xor(v0, 16); v0 += __shfl_xor(v0, 32);
  v1 += __shfl_xor(v1, 16); v1 += __shfl_xor(v1, 32);
  v2 += __shfl_xor(v2, 16); v2 += __shfl_xor(v2, 32);
  v3 += __shfl_xor(v3, 16); v3 += __shfl_xor(v3, 32);
  const int g4 = (lane & 15) * 4;
  const int h = lane >> 4;
  float4 gb = *(const float4*)(gbias + g4);
  v0 = fmaxf(0.25f * v0 + gb.x, 0.f);
  v1 = fmaxf(0.25f * v1 + gb.y, 0.f);
  v2 = fmaxf(0.25f * v2 + gb.z, 0.f);
  v3 = fmaxf(0.25f * v3 + gb.w, 0.f);
  float4 w0 = *(const float4*)(wcls + (g4 + 0) * 16 + h * 4);
  float4 w1 = *(const float4*)(wcls + (g4 + 1) * 16 + h * 4);
  float4 w2 = *(const float4*)(wcls + (g4 + 2) * 16 + h * 4);
  float4 w3 = *(const float4*)(wcls + (g4 + 3) * 16 + h * 4);
  float o0 = v0 * w0.x + v1 * w1.x + v2 * w2.x + v3 * w3.x;
  float o1 = v0 * w0.y + v1 * w1.y + v2 * w2.y + v3 * w3.y;
  float o2 = v0 * w0.z + v1 * w1.z + v2 * w2.z + v3 * w3.z;
  float o3 = v0 * w0.w + v1 * w1.w + v2 * w2.w + v3 * w3.w;
  #pragma unroll
  for (int mm = 1; mm < 16; mm <<= 1) {
    o0 += __shfl_xor(o0, mm); o1 += __shfl_xor(o1, mm);
    o2 += __shfl_xor(o2, mm); o3 += __shfl_xor(o3, mm);
  }
  if ((lane & 15) == 0) {
    float4 bcv = *(const float4*)(bcls + h * 4);
    float4 ov;
    ov.x = o0 + bcv.x; ov.y = o1 + bcv.y; ov.z = o2 + bcv.z; ov.w = o3 + bcv.w;
    *(float4*)(out + (size_t)n * 16 + h * 4) = ov;
  }
}

// ---------------------------------------------------------------------------
extern "C" void kernel_launch(void* const* d_in, const int* in_sizes, int n_in,
                              void* d_out, int out_size, void* d_ws, size_t ws_size,
                              hipStream_t stream)
{
  const float* x     = (const float*)d_in[0];
  const void*  ei    = d_in[1];
  const float* Win   = (const float*)d_in[2];
  const float* bin   = (const float*)d_in[3];
  const float* proto = (const float*)d_in[4];
  const float* Wl    = (const float*)d_in[5];
  const float* bl    = (const float*)d_in[6];
  const float* Wr    = (const float*)d_in[7];
  const float* br    = (const float*)d_in[8];
  const float* att   = (const float*)d_in[9];
  const float* gbias = (const float*)d_in[10];
  const float* wcls  = (const float*)d_in[11];
  const float* bcls  = (const float*)d_in[12];
  float* out = (float*)d_out;

  char* p = (char*)d_ws;
  size_t used = 0;
  auto carve = [&](size_t bytes) {
    char* q = p + used;
    used += (bytes + 255) & ~(size_t)255;
    return (void*)q;
  };
  int* flag_i = (int*)carve(256);
  int* deg  = (int*)carve(N_NODES * 4);
  int* off  = (int*)carve((N_NODES + 1) * 4);
  int* cur  = (int*)carve(N_NODES * 4);
  int* bsum = (int*)carve(NB_SCAN * 4);
  int* boff = (int*)carve(NB_SCAN * 4);
  int* esrc = (int*)carve(N_EDGES * 4);
  float* ha = (float*)carve((size_t)N_NODES * 68 * 4 + 512);
  u16* xls  = (u16*)carve((size_t)N_NODES * 256 * 2);
  size_t used_min = used + ((size_t)N_NODES * 256 * 2);
  u16* xrs  = (u16*)carve((size_t)N_NODES * 256 * 2);
  const bool full = ws_size >= used_min;

  k_detect<<<196, 256, 0, stream>>>(ei, flag_i, deg);
  k_haug<<<782, 256, 0, stream>>>(x, Win, bin, proto, ha);
  k_hist<<<3125, 256, 0, stream>>>(ei, flag_i, deg);
  k_lin<<<782, 256, 0, stream>>>(ha, Wl, bl, xls);
  if (full) k_lin<<<782, 256, 0, stream>>>(ha, Wr, br, xrs);
  k_scan_a<<<NB_SCAN, 256, 0, stream>>>(deg, bsum);
  k_scan_b<<<1, 256, 0, stream>>>(bsum, boff);
  k_scan_c<<<NB_SCAN, 256, 0, stream>>>(deg, boff, off, cur);
  k_scatter<<<3125, 256, 0, stream>>>(ei, flag_i, cur, esrc);
  if (full)
    k_agg<0><<<12500, 256, 0, stream>>>(xls, xrs, ha, Wr, br, esrc, off,
                                        att, gbias, wcls, bcls, out);
  else
    k_agg<1><<<12500, 256, 0, stream>>>(xls, xrs, ha, Wr, br, esrc, off,
                                        att, gbias, wcls, bcls, out);
}